// Round 4
// baseline (210.908 us; speedup 1.0000x reference)
//
#include <hip/hip_runtime.h>
#include <hip/hip_bf16.h>
#include <stdint.h>

// B=2, S=2048, D=1024, H=16, DH=64. Causal self-attention block, bf16 MFMA pipeline.

typedef __attribute__((ext_vector_type(8))) short bf16x8;   // 8 bf16 = 16B (A/B frag)
typedef __attribute__((ext_vector_type(4))) float f32x4;    // C/D frag 16x16
typedef __attribute__((ext_vector_type(16))) float f32x16;  // C/D frag 32x32
typedef __attribute__((ext_vector_type(4))) unsigned int u32x4;

typedef const __attribute__((address_space(1))) uint32_t* gp1_t;
typedef __attribute__((address_space(3))) uint32_t* lp3_t;

static __device__ __forceinline__ uint16_t f2b(float x) {
  __hip_bfloat16 h = __float2bfloat16(x);
  return *reinterpret_cast<uint16_t*>(&h);
}

// v_cvt_pk_bf16_f32: dst.lo = bf16(lo), dst.hi = bf16(hi)
static __device__ __forceinline__ uint32_t cvtpk(float lo, float hi) {
  uint32_t r;
  asm("v_cvt_pk_bf16_f32 %0, %1, %2" : "=v"(r) : "v"(lo), "v"(hi));
  return r;
}

// Stage R rows x 64 bf16 (128B = 8 chunks of 16B) tile into LDS (GEMMs only).
template <int ISSUES>
static __device__ __forceinline__ void stage64(const uint16_t* __restrict__ g, int gstride,
                                               uint8_t* lds, int t) {
#pragma unroll
  for (int i = 0; i < ISSUES; ++i) {
    int p = i * 256 + t;          // 16B-chunk index
    int row = p >> 3, c = p & 7;
    const uint16_t* src = g + row * gstride + ((c ^ (row & 7)) << 3);
    __builtin_amdgcn_global_load_lds((gp1_t)src, (lp3_t)(lds + (p & ~63) * 16), 16, 0, 0);
  }
}

// Read a 16B fragment from a swizzled [R][64] bf16 tile: 8 bf16 at (row, chunk*8).
static __device__ __forceinline__ bf16x8 ld_frag(const uint8_t* lds, int row, int chunk) {
  return *(const bf16x8*)(lds + row * 128 + (((chunk) ^ (row & 7)) << 4));
}

// ---------------- f32 -> bf16 convert ----------------
__global__ __launch_bounds__(256) void cvtk(const float* __restrict__ in,
                                            uint16_t* __restrict__ out, int n4) {
  int i = blockIdx.x * 256 + threadIdx.x;
  if (i >= n4) return;
  float4 v = ((const float4*)in)[i];
  ushort4 o;
  o.x = f2b(v.x); o.y = f2b(v.y); o.z = f2b(v.z); o.w = f2b(v.w);
  ((ushort4*)out)[i] = o;
}

// ---------------- GEMM1: qkv = x @ w_in^T + b_in ----------------
// Epilogue: Q pre-scaled by 1/sqrt(DH)*log2(e) (softmax done in exp2 domain).
// V stored transposed (B,H,DH,S) with column bits 2<->3 swapped inside each
// 16-col block, so attention's PV B-fragments are contiguous 16B loads while
// P stays fully lane-local (kv(ks,hi,j) = 32(ks>>1)+16(ks&1)+8(j>>2)+4hi+(j&3)).
__global__ __launch_bounds__(256) void gemm_qkv(const uint16_t* __restrict__ A,
                                                const uint16_t* __restrict__ W,
                                                const float* __restrict__ bias,
                                                uint16_t* __restrict__ Qb,
                                                uint16_t* __restrict__ Kb,
                                                uint16_t* __restrict__ Vt) {
  __shared__ uint8_t sm[32768];
  uint8_t* As = sm;
  uint8_t* Bs = sm + 16384;
  int t = threadIdx.x, l = t & 63, w = t >> 6;
  int m0 = blockIdx.y * 128, n0 = blockIdx.x * 128;
  int wr = (w >> 1) * 64, wc = (w & 1) * 64;
  const f32x4 fz = {0.f, 0.f, 0.f, 0.f};
  f32x4 acc[4][4];
#pragma unroll
  for (int i = 0; i < 4; ++i)
#pragma unroll
    for (int j = 0; j < 4; ++j) acc[i][j] = fz;

  for (int kt = 0; kt < 16; ++kt) {
    __syncthreads();
    stage64<4>(A + m0 * 1024 + kt * 64, 1024, As, t);
    stage64<4>(W + n0 * 1024 + kt * 64, 1024, Bs, t);
    __syncthreads();
#pragma unroll
    for (int ks = 0; ks < 2; ++ks) {
      bf16x8 a[4], b[4];
#pragma unroll
      for (int i = 0; i < 4; ++i) {
        a[i] = ld_frag(As, wr + i * 16 + (l & 15), ks * 4 + (l >> 4));
        b[i] = ld_frag(Bs, wc + i * 16 + (l & 15), ks * 4 + (l >> 4));
      }
#pragma unroll
      for (int i = 0; i < 4; ++i)
#pragma unroll
        for (int j = 0; j < 4; ++j)
          acc[i][j] = __builtin_amdgcn_mfma_f32_16x16x32_bf16(a[i], b[j], acc[i][j], 0, 0, 0);
    }
  }
  const float CSQ = 0.18033688011112042f;  // 0.125 * log2(e)
#pragma unroll
  for (int j = 0; j < 4; ++j) {
    int e = n0 + wc + j * 16 + (l & 15);
    float bv = bias[e];
    int sec = e >> 10, ec = e & 1023, h = ec >> 6, dh = ec & 63;
#pragma unroll
    for (int i = 0; i < 4; ++i) {
      int mb = m0 + wr + i * 16 + ((l >> 4) << 2);
#pragma unroll
      for (int r = 0; r < 4; ++r) {
        int m = mb + r, bb = m >> 11, s = m & 2047;
        float v = acc[i][j][r] + bv;
        if (sec == 0) {
          Qb[(((bb * 16 + h) * 2048 + s) << 6) + dh] = f2b(v * CSQ);
        } else if (sec == 1) {
          Kb[(((bb * 16 + h) * 2048 + s) << 6) + dh] = f2b(v);
        } else {
          int sp = (s & ~12) | ((s & 4) << 1) | ((s & 8) >> 1);  // swap col bits 2,3
          Vt[(((bb * 16 + h) << 6) + dh) * 2048 + sp] = f2b(v);
        }
      }
    }
  }
}

// ---------------- GEMM2: out = att @ w_out^T + b_out (f32 out) ----------------
__global__ __launch_bounds__(256) void gemm_out(const uint16_t* __restrict__ A,
                                                const uint16_t* __restrict__ W,
                                                const float* __restrict__ bias,
                                                float* __restrict__ out) {
  __shared__ uint8_t sm[32768];
  uint8_t* As = sm;
  uint8_t* Bs = sm + 16384;
  int t = threadIdx.x, l = t & 63, w = t >> 6;
  int m0 = blockIdx.y * 128, n0 = blockIdx.x * 128;
  int wr = (w >> 1) * 64, wc = (w & 1) * 64;
  const f32x4 fz = {0.f, 0.f, 0.f, 0.f};
  f32x4 acc[4][4];
#pragma unroll
  for (int i = 0; i < 4; ++i)
#pragma unroll
    for (int j = 0; j < 4; ++j) acc[i][j] = fz;

  for (int kt = 0; kt < 16; ++kt) {
    __syncthreads();
    stage64<4>(A + m0 * 1024 + kt * 64, 1024, As, t);
    stage64<4>(W + n0 * 1024 + kt * 64, 1024, Bs, t);
    __syncthreads();
#pragma unroll
    for (int ks = 0; ks < 2; ++ks) {
      bf16x8 a[4], b[4];
#pragma unroll
      for (int i = 0; i < 4; ++i) {
        a[i] = ld_frag(As, wr + i * 16 + (l & 15), ks * 4 + (l >> 4));
        b[i] = ld_frag(Bs, wc + i * 16 + (l & 15), ks * 4 + (l >> 4));
      }
#pragma unroll
      for (int i = 0; i < 4; ++i)
#pragma unroll
        for (int j = 0; j < 4; ++j)
          acc[i][j] = __builtin_amdgcn_mfma_f32_16x16x32_bf16(a[i], b[j], acc[i][j], 0, 0, 0);
    }
  }
#pragma unroll
  for (int j = 0; j < 4; ++j) {
    int e = n0 + wc + j * 16 + (l & 15);
    float bv = bias[e];
#pragma unroll
    for (int i = 0; i < 4; ++i) {
      int mb = m0 + wr + i * 16 + ((l >> 4) << 2);
#pragma unroll
      for (int r = 0; r < 4; ++r) {
        int m = mb + r;
        out[m * 1024 + e] = acc[i][j][r] + bv;
      }
    }
  }
}

// ---------------- Flash attention (causal): 1 wave/block, registers-only ----------------
// Grid (64 qt [reversed], 32 bh), 64 threads. Each wave owns 32 q rows; no LDS,
// no barriers. K/V fragments loaded global->reg (V pre-permuted by gemm_qkv).
// Swapped QK^T: sc = mfma32(A=K, B=Q), lane owns q=lane&31,
// kv rows = (r&3)+8*(r>>2)+4*hi per 32-row frag. Softmax in-register (exp2 domain,
// Q pre-scaled). PV: lane-local P (permuted k-slots), contiguous V frags.
__global__ __launch_bounds__(64) void attn(const uint16_t* __restrict__ Qb,
                                           const uint16_t* __restrict__ Kb,
                                           const uint16_t* __restrict__ Vt,
                                           uint16_t* __restrict__ Ab,
                                           const int* __restrict__ maskp) {
  int l = threadIdx.x & 63;
  int hi = l >> 5, ql = l & 31;
  int qt = 63 - (int)blockIdx.x;    // heavy blocks dispatched first
  int bh = blockIdx.y;
  bool causal = (*maskp != 0);
  int nt = causal ? ((qt >> 1) + 1) : 32;
  int q0 = qt * 32;
  int q = q0 + ql;

  // Q fragments (B-operand): Q[q][dh = ks*16 + hi*8 + j], pre-scaled by CSQ
  bf16x8 qf[4];
  const uint16_t* Qp = Qb + (((size_t)bh * 2048 + q) << 6) + hi * 8;
#pragma unroll
  for (int ks = 0; ks < 4; ++ks) qf[ks] = *(const bf16x8*)(Qp + ks * 16);

  const uint16_t* Kp = Kb + (((size_t)bh * 2048) << 6) + (ql << 6) + hi * 8;
  const uint16_t* Vp = Vt + (size_t)bh * 131072 + (size_t)ql * 2048 + hi * 8;

  f32x16 acco[2];
#pragma unroll
  for (int r = 0; r < 16; ++r) { acco[0][r] = 0.f; acco[1][r] = 0.f; }
  float mrun = -1e30f, lsum = 0.f;

  for (int tt = 0; tt < nt; ++tt) {
    // K frags: kf[f][ks] = K[tt*64 + f*32 + ql][ks*16 + hi*8 ..+7]
    bf16x8 kf[2][4], vf[2][4];
    const uint16_t* kp = Kp + (tt << 12);
#pragma unroll
    for (int f = 0; f < 2; ++f)
#pragma unroll
      for (int ks = 0; ks < 4; ++ks)
        kf[f][ks] = *(const bf16x8*)(kp + (f << 11) + ks * 16);
    // V frags (permuted columns): vf[n][ks] @ row dh=n*32+ql, cols tt*64+ks*16+hi*8
    const uint16_t* vp = Vp + tt * 64;
#pragma unroll
    for (int n = 0; n < 2; ++n)
#pragma unroll
      for (int ks = 0; ks < 4; ++ks)
        vf[n][ks] = *(const bf16x8*)(vp + n * 65536 + ks * 16);

    // QK^T: sc[f][r] = S[kv = tt*64 + f*32 + crow(r,hi)][q]  (already exp2-scaled)
    f32x16 sc[2];
#pragma unroll
    for (int r = 0; r < 16; ++r) { sc[0][r] = 0.f; sc[1][r] = 0.f; }
    __builtin_amdgcn_s_setprio(1);
#pragma unroll
    for (int f = 0; f < 2; ++f)
#pragma unroll
      for (int ks = 0; ks < 4; ++ks)
        sc[f] = __builtin_amdgcn_mfma_f32_32x32x16_bf16(kf[f][ks], qf[ks], sc[f], 0, 0, 0);
    __builtin_amdgcn_s_setprio(0);

    // causal mask + running max (in place on sc)
    float tm = -1e30f;
    bool nomask = (!causal) || (tt * 64 + 63 <= q0);
#pragma unroll
    for (int f = 0; f < 2; ++f)
#pragma unroll
      for (int r = 0; r < 16; ++r) {
        float v = sc[f][r];
        if (!nomask) {
          int kv = tt * 64 + f * 32 + ((r & 3) + 8 * (r >> 2) + 4 * hi);
          v = (kv <= q) ? v : -1e30f;
        }
        sc[f][r] = v;
        tm = fmaxf(tm, v);
      }
    tm = fmaxf(tm, __shfl_xor(tm, 32));

    // defer-max (T13): skip rescale when max growth small
    bool defer = __all(tm <= mrun + 8.0f);
    if (!defer) {
      float mnew = fmaxf(mrun, tm);
      float alpha = exp2f(mrun - mnew);
      mrun = mnew;
      lsum *= alpha;
#pragma unroll
      for (int r = 0; r < 16; ++r) {
        float av = __shfl(alpha, (r & 3) + 8 * (r >> 2) + 4 * hi);
        acco[0][r] *= av;
        acco[1][r] *= av;
      }
    }
    float rs = 0.f;
#pragma unroll
    for (int f = 0; f < 2; ++f)
#pragma unroll
      for (int r = 0; r < 16; ++r) {
        float e = exp2f(sc[f][r] - mrun);
        sc[f][r] = e;
        rs += e;
      }
    rs += __shfl_xor(rs, 32);
    lsum += rs;

    // PV with lane-local P fragments (zero cross-lane):
    __builtin_amdgcn_s_setprio(1);
#pragma unroll
    for (int ks = 0; ks < 4; ++ks) {
      int f = ks >> 1, a8 = (ks & 1) * 8;
      u32x4 wv = {cvtpk(sc[f][a8 + 0], sc[f][a8 + 1]),
                  cvtpk(sc[f][a8 + 2], sc[f][a8 + 3]),
                  cvtpk(sc[f][a8 + 4], sc[f][a8 + 5]),
                  cvtpk(sc[f][a8 + 6], sc[f][a8 + 7])};
      bf16x8 af = __builtin_bit_cast(bf16x8, wv);
#pragma unroll
      for (int n = 0; n < 2; ++n)
        acco[n] = __builtin_amdgcn_mfma_f32_32x32x16_bf16(af, vf[n][ks], acco[n], 0, 0, 0);
    }
    __builtin_amdgcn_s_setprio(0);
  }

  // epilogue: O[q = q0 + crow(r,hi)][dh = n*32 + ql] / lsum[q]
  int bb = bh >> 4, h = bh & 15;
#pragma unroll
  for (int r = 0; r < 16; ++r) {
    int crow = (r & 3) + 8 * (r >> 2) + 4 * hi;
    float ls = __shfl(lsum, crow);
    float inv = 1.0f / ls;
    int qg = q0 + crow;
#pragma unroll
    for (int n = 0; n < 2; ++n)
      Ab[(((size_t)(bb * 2048 + qg)) << 10) + h * 64 + n * 32 + ql] = f2b(acco[n][r] * inv);
  }
}

extern "C" void kernel_launch(void* const* d_in, const int* in_sizes, int n_in,
                              void* d_out, int out_size, void* d_ws, size_t ws_size,
                              hipStream_t stream) {
  const float* x     = (const float*)d_in[0];
  const float* w_in  = (const float*)d_in[1];
  const float* b_in  = (const float*)d_in[2];
  const float* w_out = (const float*)d_in[3];
  const float* b_out = (const float*)d_in[4];
  const int*   mask  = (const int*)d_in[5];
  float* out = (float*)d_out;

  uint8_t* ws = (uint8_t*)d_ws;
  uint16_t* xb  = (uint16_t*)(ws);                  // 8 MB  x bf16 [4096][1024]
  uint16_t* wib = (uint16_t*)(ws + (8u << 20));     // 6 MB  w_in bf16 [3072][1024]
  uint16_t* wob = (uint16_t*)(ws + (14u << 20));    // 2 MB  w_out bf16 [1024][1024]
  uint16_t* Qb  = (uint16_t*)(ws + (16u << 20));    // 8 MB  (B,H,S,DH) pre-scaled
  uint16_t* Kb  = (uint16_t*)(ws + (24u << 20));    // 8 MB  (B,H,S,DH)
  uint16_t* Vt  = (uint16_t*)(ws + (32u << 20));    // 8 MB  (B,H,DH,S) col-permuted
  uint16_t* Ab  = (uint16_t*)(ws + (40u << 20));    // 8 MB  att (B,S,D) bf16

  cvtk<<<4096, 256, 0, stream>>>(x, xb, 4096 * 1024 / 4);
  cvtk<<<3072, 256, 0, stream>>>(w_in, wib, 3072 * 1024 / 4);
  cvtk<<<1024, 256, 0, stream>>>(w_out, wob, 1024 * 1024 / 4);
  gemm_qkv<<<dim3(24, 32), 256, 0, stream>>>(xb, wib, b_in, Qb, Kb, Vt);
  attn<<<dim3(64, 32), 64, 0, stream>>>(Qb, Kb, Vt, Ab, mask);
  gemm_out<<<dim3(8, 32), 256, 0, stream>>>(Ab, wob, b_out, out);
}